// Round 1
// baseline (86.721 us; speedup 1.0000x reference)
//
#include <hip/hip_runtime.h>

#define HW        128
#define PLANE     (HW * HW)        // 16384
#define NCH       64
#define NB        32
#define NPLANES   (NB * NCH)       // 2048
#define HALF_ROWS 64
#define LDS_ROWS  66               // 64 interior + 2 halo
#define LDS_STR   136              // 128 interior + 4 left pad + 4 right pad (16B-aligned rows)
#define COUNT_INV (1.0f / 524288.0f)
#define EPSV      1e-5f

// ws layout (floats):
//   [0 .. 8191]      per-block sum partials   (index = plane*2 + half)
//   [8192 .. 16383]  per-block sumsq partials
//   [16384 .. 16447] scale[c]
//   [16448 .. 16511] shift[c]

__device__ __forceinline__ void stage_halfplane(const float* __restrict__ x,
                                                int plane, int half, float* ld) {
    const int t = threadIdx.x;
    // zero everything (halo stays zero)
    for (int i = t; i < LDS_ROWS * LDS_STR; i += 256) ld[i] = 0.f;
    __syncthreads();
    const float4* xp = (const float4*)(x + (size_t)plane * PLANE);
    const int h0base = half * HALF_ROWS;
    // 66 rows x 32 float4 = 2112 float4 loads
    for (int f = t; f < LDS_ROWS * 32; f += 256) {
        int r  = f >> 5;          // LDS row 0..65
        int c4 = f & 31;
        int g  = h0base - 1 + r;  // global row
        if ((unsigned)g < (unsigned)HW) {
            float4 v = xp[g * 32 + c4];
            *(float4*)&ld[r * LDS_STR + 4 + c4 * 4] = v;
        }
    }
    __syncthreads();
}

// conv for a 4-row column strip; returns 4 accumulators
__device__ __forceinline__ void conv4(const float* ld, int h0l, int wcol,
                                      const float* W, float bias, float acc[4]) {
    float v[6][3];
#pragma unroll
    for (int i = 0; i < 6; ++i)
#pragma unroll
        for (int j = 0; j < 3; ++j)
            v[i][j] = ld[(h0l + i) * LDS_STR + wcol + 3 + j];
#pragma unroll
    for (int k = 0; k < 4; ++k) {
        float a = bias;
#pragma unroll
        for (int kh = 0; kh < 3; ++kh)
#pragma unroll
            for (int kw = 0; kw < 3; ++kw)
                a = fmaf(v[k + kh][kw], W[kh * 3 + kw], a);
        acc[k] = a;
    }
}

__global__ __launch_bounds__(256) void dwconv_reduce(const float* __restrict__ x,
                                                     const float* __restrict__ wgt,
                                                     const float* __restrict__ bias,
                                                     float* __restrict__ partials) {
    __shared__ float ld[LDS_ROWS * LDS_STR];
    __shared__ float red[8];
    const int bid   = blockIdx.x;      // 0..4095
    const int plane = bid >> 1;        // n*64 + c
    const int half  = bid & 1;
    const int c     = plane & 63;
    const int t     = threadIdx.x;

    float W[9];
#pragma unroll
    for (int k = 0; k < 9; ++k) W[k] = wgt[c * 9 + k];
    const float bv = bias[c];

    stage_halfplane(x, plane, half, ld);

    const int wcol = t & 127;
    const int trow = t >> 7;           // 0 or 1
    float sum = 0.f, sq = 0.f;
#pragma unroll
    for (int jj = 0; jj < 8; ++jj) {
        int h0l = (trow + jj * 2) * 4; // 0..60 step 4 across the two thread-rows
        float acc[4];
        conv4(ld, h0l, wcol, W, bv, acc);
#pragma unroll
        for (int k = 0; k < 4; ++k) {
            sum += acc[k];
            sq   = fmaf(acc[k], acc[k], sq);
        }
    }
    // wave64 reduce
#pragma unroll
    for (int off = 32; off; off >>= 1) {
        sum += __shfl_down(sum, off);
        sq  += __shfl_down(sq, off);
    }
    const int wave = t >> 6, lane = t & 63;
    if (lane == 0) { red[wave] = sum; red[4 + wave] = sq; }
    __syncthreads();
    if (t == 0) {
        float S = red[0] + red[1] + red[2] + red[3];
        float Q = red[4] + red[5] + red[6] + red[7];
        partials[bid]        = S;
        partials[8192 + bid] = Q;
    }
}

__global__ void bn_stats(const float* __restrict__ partials,
                         const float* __restrict__ gamma,
                         const float* __restrict__ beta,
                         float* __restrict__ st) {
    int c = threadIdx.x;
    if (c < NCH) {
        float S = 0.f, Q = 0.f;
        for (int n = 0; n < NB; ++n) {
            int base = (n * NCH + c) * 2;
            S += partials[base] + partials[base + 1];
            Q += partials[8192 + base] + partials[8192 + base + 1];
        }
        float mean = S * COUNT_INV;
        float var  = fmaxf(Q * COUNT_INV - mean * mean, 0.f);
        float s    = gamma[c] * rsqrtf(var + EPSV);
        st[c]        = s;
        st[NCH + c]  = beta[c] - mean * s;
    }
}

__global__ __launch_bounds__(256) void dwconv_apply(const float* __restrict__ x,
                                                    const float* __restrict__ wgt,
                                                    const float* __restrict__ bias,
                                                    const float* __restrict__ st,
                                                    float* __restrict__ out) {
    __shared__ float ld[LDS_ROWS * LDS_STR];
    const int bid   = blockIdx.x;
    const int plane = bid >> 1;
    const int half  = bid & 1;
    const int c     = plane & 63;
    const int t     = threadIdx.x;

    float W[9];
#pragma unroll
    for (int k = 0; k < 9; ++k) W[k] = wgt[c * 9 + k];
    const float bv = bias[c];
    const float s  = st[c];
    const float sh = st[NCH + c];

    stage_halfplane(x, plane, half, ld);

    const int wcol = t & 127;
    const int trow = t >> 7;
    float* op = out + (size_t)plane * PLANE + (size_t)(half * HALF_ROWS) * HW;
#pragma unroll
    for (int jj = 0; jj < 8; ++jj) {
        int h0l = (trow + jj * 2) * 4;
        float acc[4];
        conv4(ld, h0l, wcol, W, bv, acc);
#pragma unroll
        for (int k = 0; k < 4; ++k) {
            float r = fmaf(acc[k], s, sh);
            op[(h0l + k) * HW + wcol] = fmaxf(r, 0.f);
        }
    }
}

extern "C" void kernel_launch(void* const* d_in, const int* in_sizes, int n_in,
                              void* d_out, int out_size, void* d_ws, size_t ws_size,
                              hipStream_t stream) {
    const float* x     = (const float*)d_in[0];
    const float* w     = (const float*)d_in[1];
    const float* b     = (const float*)d_in[2];
    const float* gamma = (const float*)d_in[3];
    const float* beta  = (const float*)d_in[4];
    float* out = (float*)d_out;
    float* ws  = (float*)d_ws;

    dwconv_reduce<<<NPLANES * 2, 256, 0, stream>>>(x, w, b, ws);
    bn_stats<<<1, 64, 0, stream>>>(ws, gamma, beta, ws + 16384);
    dwconv_apply<<<NPLANES * 2, 256, 0, stream>>>(x, w, b, ws + 16384, out);
}

// Round 2
// 79.173 us; speedup vs baseline: 1.0953x; 1.0953x over previous
//
#include <hip/hip_runtime.h>

#define HW        128
#define PLANE     16384            // 128*128
#define NCH       64
#define NB        32
#define NPLANES   2048             // NB*NCH
#define COUNT_INV (1.0f / 524288.0f)
#define EPSV      1e-5f

// ws layout (floats):
//   [0 .. 2047]      per-plane sum   (index = n*64 + c)
//   [2048 .. 4095]   per-plane sumsq

// Load one input row's 6-wide window (cols w4-1 .. w4+4) into v[6].
// Rows outside [0,128) and cols outside [0,128) are zero (conv padding).
__device__ __forceinline__ void load_row(const float* __restrict__ bp, int g, int w4,
                                         bool hasL, bool hasR, float (&v)[6]) {
    if ((unsigned)g < (unsigned)HW) {
        const float* rp = bp + g * HW + w4;
        float4 m = *(const float4*)rp;
        v[0] = hasL ? rp[-1] : 0.f;
        v[1] = m.x; v[2] = m.y; v[3] = m.z; v[4] = m.w;
        v[5] = hasR ? rp[4] : 0.f;
    } else {
        v[0] = 0.f; v[1] = 0.f; v[2] = 0.f; v[3] = 0.f; v[4] = 0.f; v[5] = 0.f;
    }
}

// 3x3 conv producing 4 adjacent outputs from the 3-row x 6-col window.
__device__ __forceinline__ void conv_row(const float (&tp)[6], const float (&md)[6],
                                         const float (&bt)[6], const float* W,
                                         float bias, float (&acc)[4]) {
#pragma unroll
    for (int j = 0; j < 4; ++j) {
        float a = bias;
        a = fmaf(tp[j],     W[0], a);
        a = fmaf(tp[j + 1], W[1], a);
        a = fmaf(tp[j + 2], W[2], a);
        a = fmaf(md[j],     W[3], a);
        a = fmaf(md[j + 1], W[4], a);
        a = fmaf(md[j + 2], W[5], a);
        a = fmaf(bt[j],     W[6], a);
        a = fmaf(bt[j + 1], W[7], a);
        a = fmaf(bt[j + 2], W[8], a);
        acc[j] = a;
    }
}

__global__ __launch_bounds__(256, 4) void pass_stats(const float* __restrict__ x,
                                                     const float* __restrict__ wgt,
                                                     const float* __restrict__ bias,
                                                     float* __restrict__ partials) {
    __shared__ float red[8];
    const int p  = blockIdx.x;           // n*64 + c
    const int c  = p & 63;
    const int t  = threadIdx.x;
    const int cg = t & 31, rg = t >> 5;
    const int w4 = cg * 4, r0 = rg * 16;

    float W[9];
#pragma unroll
    for (int k = 0; k < 9; ++k) W[k] = wgt[c * 9 + k];
    const float bv = bias[c];
    const float* bp = x + (size_t)p * PLANE;
    const bool hasL = (cg != 0), hasR = (cg != 31);

    float v[3][6];
    load_row(bp, r0 - 1, w4, hasL, hasR, v[0]);
    load_row(bp, r0,     w4, hasL, hasR, v[1]);

    float sum = 0.f, sq = 0.f;
#pragma unroll
    for (int i = 0; i < 16; ++i) {
        load_row(bp, r0 + 1 + i, w4, hasL, hasR, v[(i + 2) % 3]);
        float acc[4];
        conv_row(v[i % 3], v[(i + 1) % 3], v[(i + 2) % 3], W, bv, acc);
#pragma unroll
        for (int j = 0; j < 4; ++j) {
            sum += acc[j];
            sq = fmaf(acc[j], acc[j], sq);
        }
    }

#pragma unroll
    for (int off = 32; off; off >>= 1) {
        sum += __shfl_down(sum, off);
        sq  += __shfl_down(sq, off);
    }
    const int wave = t >> 6, lane = t & 63;
    if (lane == 0) { red[wave] = sum; red[4 + wave] = sq; }
    __syncthreads();
    if (t == 0) {
        partials[p]           = red[0] + red[1] + red[2] + red[3];
        partials[NPLANES + p] = red[4] + red[5] + red[6] + red[7];
    }
}

__global__ __launch_bounds__(256, 4) void pass_apply(const float* __restrict__ x,
                                                     const float* __restrict__ wgt,
                                                     const float* __restrict__ bias,
                                                     const float* __restrict__ partials,
                                                     const float* __restrict__ gamma,
                                                     const float* __restrict__ beta,
                                                     float* __restrict__ out) {
    __shared__ float ssh[2];
    const int p  = blockIdx.x;
    const int c  = p & 63;
    const int t  = threadIdx.x;
    const int cg = t & 31, rg = t >> 5;
    const int w4 = cg * 4, r0 = rg * 16;

    // per-channel stats: one wave folds the 32 per-plane partial pairs
    if (t < 32) {
        float S = partials[t * NCH + c];
        float Q = partials[NPLANES + t * NCH + c];
#pragma unroll
        for (int off = 16; off; off >>= 1) {
            S += __shfl_down(S, off);
            Q += __shfl_down(Q, off);
        }
        if (t == 0) {
            float mean = S * COUNT_INV;
            float var  = fmaxf(Q * COUNT_INV - mean * mean, 0.f);
            float s    = gamma[c] * rsqrtf(var + EPSV);
            ssh[0] = s;
            ssh[1] = beta[c] - mean * s;
        }
    }

    float W[9];
#pragma unroll
    for (int k = 0; k < 9; ++k) W[k] = wgt[c * 9 + k];
    const float bv = bias[c];
    __syncthreads();
    const float s  = ssh[0];
    const float sh = fmaf(bv, s, ssh[1]);   // fold conv bias into BN shift

    const float* bp = x + (size_t)p * PLANE;
    float* op = out + (size_t)p * PLANE;
    const bool hasL = (cg != 0), hasR = (cg != 31);

    float v[3][6];
    load_row(bp, r0 - 1, w4, hasL, hasR, v[0]);
    load_row(bp, r0,     w4, hasL, hasR, v[1]);

#pragma unroll
    for (int i = 0; i < 16; ++i) {
        load_row(bp, r0 + 1 + i, w4, hasL, hasR, v[(i + 2) % 3]);
        float acc[4];
        conv_row(v[i % 3], v[(i + 1) % 3], v[(i + 2) % 3], W, 0.f, acc);
        float4 o;
        o.x = fmaxf(fmaf(acc[0], s, sh), 0.f);
        o.y = fmaxf(fmaf(acc[1], s, sh), 0.f);
        o.z = fmaxf(fmaf(acc[2], s, sh), 0.f);
        o.w = fmaxf(fmaf(acc[3], s, sh), 0.f);
        *(float4*)(op + (r0 + i) * HW + w4) = o;
    }
}

extern "C" void kernel_launch(void* const* d_in, const int* in_sizes, int n_in,
                              void* d_out, int out_size, void* d_ws, size_t ws_size,
                              hipStream_t stream) {
    const float* x     = (const float*)d_in[0];
    const float* w     = (const float*)d_in[1];
    const float* b     = (const float*)d_in[2];
    const float* gamma = (const float*)d_in[3];
    const float* beta  = (const float*)d_in[4];
    float* out = (float*)d_out;
    float* ws  = (float*)d_ws;

    pass_stats<<<NPLANES, 256, 0, stream>>>(x, w, b, ws);
    pass_apply<<<NPLANES, 256, 0, stream>>>(x, w, b, ws, gamma, beta, out);
}

// Round 3
// 78.816 us; speedup vs baseline: 1.1003x; 1.0045x over previous
//
#include <hip/hip_runtime.h>
#include <hip/hip_cooperative_groups.h>

namespace cg = cooperative_groups;

#define HW        128
#define PLANE     16384            // 128*128
#define NCH       64
#define NB        32
#define NPLANES   2048             // NB*NCH
#define COUNT_INV (1.0f / 524288.0f)
#define EPSV      1e-5f
#define GRID_F    1024             // fused: 1024 blocks x 2 planes (same channel)

// ws layout (floats):
//   [0 .. 2047]      per-plane sum   (index = n*64 + c)
//   [2048 .. 4095]   per-plane sumsq

__device__ __forceinline__ void load_row(const float* __restrict__ bp, int g, int w4,
                                         bool hasL, bool hasR, float (&v)[6]) {
    if ((unsigned)g < (unsigned)HW) {
        const float* rp = bp + g * HW + w4;
        float4 m = *(const float4*)rp;
        v[0] = hasL ? rp[-1] : 0.f;
        v[1] = m.x; v[2] = m.y; v[3] = m.z; v[4] = m.w;
        v[5] = hasR ? rp[4] : 0.f;
    } else {
        v[0] = 0.f; v[1] = 0.f; v[2] = 0.f; v[3] = 0.f; v[4] = 0.f; v[5] = 0.f;
    }
}

__device__ __forceinline__ void conv_row(const float (&tp)[6], const float (&md)[6],
                                         const float (&bt)[6], const float* W,
                                         float bias, float (&acc)[4]) {
#pragma unroll
    for (int j = 0; j < 4; ++j) {
        float a = bias;
        a = fmaf(tp[j],     W[0], a);
        a = fmaf(tp[j + 1], W[1], a);
        a = fmaf(tp[j + 2], W[2], a);
        a = fmaf(md[j],     W[3], a);
        a = fmaf(md[j + 1], W[4], a);
        a = fmaf(md[j + 2], W[5], a);
        a = fmaf(bt[j],     W[6], a);
        a = fmaf(bt[j + 1], W[7], a);
        a = fmaf(bt[j + 2], W[8], a);
        acc[j] = a;
    }
}

// conv over this thread's 16x4 patch, accumulating sum/sumsq
__device__ __forceinline__ void plane_sums(const float* __restrict__ bp, int r0, int w4,
                                           bool hasL, bool hasR, const float* W,
                                           float bv, float& sum, float& sq) {
    float v[3][6];
    load_row(bp, r0 - 1, w4, hasL, hasR, v[0]);
    load_row(bp, r0,     w4, hasL, hasR, v[1]);
    sum = 0.f; sq = 0.f;
#pragma unroll
    for (int i = 0; i < 16; ++i) {
        load_row(bp, r0 + 1 + i, w4, hasL, hasR, v[(i + 2) % 3]);
        float acc[4];
        conv_row(v[i % 3], v[(i + 1) % 3], v[(i + 2) % 3], W, bv, acc);
#pragma unroll
        for (int j = 0; j < 4; ++j) {
            sum += acc[j];
            sq = fmaf(acc[j], acc[j], sq);
        }
    }
}

// conv over this thread's 16x4 patch, apply scale/shift + relu, store float4
__device__ __forceinline__ void plane_store(const float* __restrict__ bp,
                                            float* __restrict__ op, int r0, int w4,
                                            bool hasL, bool hasR, const float* W,
                                            float s, float sh) {
    float v[3][6];
    load_row(bp, r0 - 1, w4, hasL, hasR, v[0]);
    load_row(bp, r0,     w4, hasL, hasR, v[1]);
#pragma unroll
    for (int i = 0; i < 16; ++i) {
        load_row(bp, r0 + 1 + i, w4, hasL, hasR, v[(i + 2) % 3]);
        float acc[4];
        conv_row(v[i % 3], v[(i + 1) % 3], v[(i + 2) % 3], W, 0.f, acc);
        float4 o;
        o.x = fmaxf(fmaf(acc[0], s, sh), 0.f);
        o.y = fmaxf(fmaf(acc[1], s, sh), 0.f);
        o.z = fmaxf(fmaf(acc[2], s, sh), 0.f);
        o.w = fmaxf(fmaf(acc[3], s, sh), 0.f);
        *(float4*)(op + (r0 + i) * HW + w4) = o;
    }
}

// ------------------------- fused cooperative kernel -------------------------
__global__ __launch_bounds__(256, 4) void fused(const float* __restrict__ x,
                                                const float* __restrict__ wgt,
                                                const float* __restrict__ bias,
                                                const float* __restrict__ gamma,
                                                const float* __restrict__ beta,
                                                float* __restrict__ partials,
                                                float* __restrict__ out) {
    __shared__ float red[8];
    __shared__ float ssh[2];
    const int bid = blockIdx.x;        // 0..1023
    const int c   = bid & 63;
    const int np  = bid >> 6;          // 0..15 -> planes n=2np, 2np+1, channel c
    const int t   = threadIdx.x;
    const int cg_ = t & 31, rg = t >> 5;
    const int w4  = cg_ * 4, r0 = rg * 16;
    const bool hasL = (cg_ != 0), hasR = (cg_ != 31);

    float W[9];
#pragma unroll
    for (int k = 0; k < 9; ++k) W[k] = wgt[c * 9 + k];
    const float bv = bias[c];

    // ---- phase 1: conv + per-plane sum/sumsq for both planes ----
    for (int pp = 0; pp < 2; ++pp) {
        const int p = (np * 2 + pp) * NCH + c;
        const float* bp = x + (size_t)p * PLANE;
        float sum, sq;
        plane_sums(bp, r0, w4, hasL, hasR, W, bv, sum, sq);
#pragma unroll
        for (int off = 32; off; off >>= 1) {
            sum += __shfl_down(sum, off);
            sq  += __shfl_down(sq, off);
        }
        const int wave = t >> 6, lane = t & 63;
        if (lane == 0) { red[wave] = sum; red[4 + wave] = sq; }
        __syncthreads();
        if (t == 0) {
            partials[p]           = red[0] + red[1] + red[2] + red[3];
            partials[NPLANES + p] = red[4] + red[5] + red[6] + red[7];
        }
        __syncthreads();
    }
    __threadfence();
    cg::this_grid().sync();

    // ---- stats fold: one 32-lane group folds channel c's 32 plane-partials ----
    if (t < 32) {
        float S = partials[t * NCH + c];
        float Q = partials[NPLANES + t * NCH + c];
#pragma unroll
        for (int off = 16; off; off >>= 1) {
            S += __shfl_down(S, off);
            Q += __shfl_down(Q, off);
        }
        if (t == 0) {
            float mean = S * COUNT_INV;
            float var  = fmaxf(Q * COUNT_INV - mean * mean, 0.f);
            float s    = gamma[c] * rsqrtf(var + EPSV);
            ssh[0] = s;
            ssh[1] = beta[c] - mean * s;
        }
    }
    __syncthreads();
    const float s  = ssh[0];
    const float sh = fmaf(bv, s, ssh[1]);   // fold conv bias into BN shift

    // ---- phase 2: recompute conv, normalize, relu, store (reverse order for L2) ----
    for (int pp = 1; pp >= 0; --pp) {
        const int p = (np * 2 + pp) * NCH + c;
        const float* bp = x + (size_t)p * PLANE;
        float* op = out + (size_t)p * PLANE;
        plane_store(bp, op, r0, w4, hasL, hasR, W, s, sh);
    }
}

// ------------------------- fallback two-kernel path -------------------------
__global__ __launch_bounds__(256, 4) void pass_stats(const float* __restrict__ x,
                                                     const float* __restrict__ wgt,
                                                     const float* __restrict__ bias,
                                                     float* __restrict__ partials) {
    __shared__ float red[8];
    const int p  = blockIdx.x;
    const int c  = p & 63;
    const int t  = threadIdx.x;
    const int cg_ = t & 31, rg = t >> 5;
    const int w4 = cg_ * 4, r0 = rg * 16;
    const bool hasL = (cg_ != 0), hasR = (cg_ != 31);

    float W[9];
#pragma unroll
    for (int k = 0; k < 9; ++k) W[k] = wgt[c * 9 + k];
    const float bv = bias[c];
    const float* bp = x + (size_t)p * PLANE;

    float sum, sq;
    plane_sums(bp, r0, w4, hasL, hasR, W, bv, sum, sq);
#pragma unroll
    for (int off = 32; off; off >>= 1) {
        sum += __shfl_down(sum, off);
        sq  += __shfl_down(sq, off);
    }
    const int wave = t >> 6, lane = t & 63;
    if (lane == 0) { red[wave] = sum; red[4 + wave] = sq; }
    __syncthreads();
    if (t == 0) {
        partials[p]           = red[0] + red[1] + red[2] + red[3];
        partials[NPLANES + p] = red[4] + red[5] + red[6] + red[7];
    }
}

__global__ __launch_bounds__(256, 4) void pass_apply(const float* __restrict__ x,
                                                     const float* __restrict__ wgt,
                                                     const float* __restrict__ bias,
                                                     const float* __restrict__ partials,
                                                     const float* __restrict__ gamma,
                                                     const float* __restrict__ beta,
                                                     float* __restrict__ out) {
    __shared__ float ssh[2];
    const int p  = blockIdx.x;
    const int c  = p & 63;
    const int t  = threadIdx.x;
    const int cg_ = t & 31, rg = t >> 5;
    const int w4 = cg_ * 4, r0 = rg * 16;
    const bool hasL = (cg_ != 0), hasR = (cg_ != 31);

    if (t < 32) {
        float S = partials[t * NCH + c];
        float Q = partials[NPLANES + t * NCH + c];
#pragma unroll
        for (int off = 16; off; off >>= 1) {
            S += __shfl_down(S, off);
            Q += __shfl_down(Q, off);
        }
        if (t == 0) {
            float mean = S * COUNT_INV;
            float var  = fmaxf(Q * COUNT_INV - mean * mean, 0.f);
            float s    = gamma[c] * rsqrtf(var + EPSV);
            ssh[0] = s;
            ssh[1] = beta[c] - mean * s;
        }
    }

    float W[9];
#pragma unroll
    for (int k = 0; k < 9; ++k) W[k] = wgt[c * 9 + k];
    const float bv = bias[c];
    __syncthreads();
    const float s  = ssh[0];
    const float sh = fmaf(bv, s, ssh[1]);

    const float* bp = x + (size_t)p * PLANE;
    float* op = out + (size_t)p * PLANE;
    plane_store(bp, op, r0, w4, hasL, hasR, W, s, sh);
}

extern "C" void kernel_launch(void* const* d_in, const int* in_sizes, int n_in,
                              void* d_out, int out_size, void* d_ws, size_t ws_size,
                              hipStream_t stream) {
    const float* x     = (const float*)d_in[0];
    const float* w     = (const float*)d_in[1];
    const float* b     = (const float*)d_in[2];
    const float* gamma = (const float*)d_in[3];
    const float* beta  = (const float*)d_in[4];
    float* out = (float*)d_out;
    float* ws  = (float*)d_ws;

    int nb = 0;
    hipError_t qe = hipOccupancyMaxActiveBlocksPerMultiprocessor(
        &nb, reinterpret_cast<const void*>(fused), 256, 0);

    if (qe == hipSuccess && nb >= 4) {
        const float* xa = x; const float* wa = w; const float* ba = b;
        const float* ga = gamma; const float* be = beta;
        float* pw = ws; float* oa = out;
        void* args[] = {&xa, &wa, &ba, &ga, &be, &pw, &oa};
        hipLaunchCooperativeKernel(reinterpret_cast<const void*>(fused),
                                   dim3(GRID_F), dim3(256), args, 0, stream);
    } else {
        pass_stats<<<NPLANES, 256, 0, stream>>>(x, w, b, ws);
        pass_apply<<<NPLANES, 256, 0, stream>>>(x, w, b, ws, gamma, beta, out);
    }
}

// Round 4
// 75.017 us; speedup vs baseline: 1.1560x; 1.0506x over previous
//
#include <hip/hip_runtime.h>

#define HW        128
#define PLANE     16384            // 128*128
#define NCH       64
#define NB        32
#define NQ        4                // quarter-planes (32 rows each)
#define NPART     8192             // NB*NCH*NQ partials per array
#define COUNT_INV (1.0f / 524288.0f)
#define EPSV      1e-5f

typedef float f4v __attribute__((ext_vector_type(4)));

// ws layout (floats):
//   [0     .. 8191]   per-quarter sum,   transposed: idx = c*128 + (n*4+q)
//   [8192  .. 16383]  per-quarter sumsq, same layout

// Load the full 6-row x 6-col input window into registers.
// All 18 load instructions are independent -> issued before first use.
__device__ __forceinline__ void load_win(const float* __restrict__ bp, int r0, int w4,
                                         bool hasL, bool hasR, float (&v)[6][6]) {
#pragma unroll
    for (int i = 0; i < 6; ++i) {
        int g = r0 - 1 + i;
        if ((unsigned)g < (unsigned)HW) {
            const float* rp = bp + g * HW + w4;
            float4 m = *(const float4*)rp;
            v[i][0] = hasL ? rp[-1] : 0.f;
            v[i][1] = m.x; v[i][2] = m.y; v[i][3] = m.z; v[i][4] = m.w;
            v[i][5] = hasR ? rp[4] : 0.f;
        } else {
#pragma unroll
            for (int j = 0; j < 6; ++j) v[i][j] = 0.f;
        }
    }
}

__device__ __forceinline__ void conv_row(const float (&tp)[6], const float (&md)[6],
                                         const float (&bt)[6], const float* W,
                                         float bias, float (&acc)[4]) {
#pragma unroll
    for (int j = 0; j < 4; ++j) {
        float a = bias;
        a = fmaf(tp[j],     W[0], a);
        a = fmaf(tp[j + 1], W[1], a);
        a = fmaf(tp[j + 2], W[2], a);
        a = fmaf(md[j],     W[3], a);
        a = fmaf(md[j + 1], W[4], a);
        a = fmaf(md[j + 2], W[5], a);
        a = fmaf(bt[j],     W[6], a);
        a = fmaf(bt[j + 1], W[7], a);
        a = fmaf(bt[j + 2], W[8], a);
        acc[j] = a;
    }
}

// ---------------- pass 1: conv + per-quarter sum/sumsq ----------------
__global__ __launch_bounds__(256) void pass_stats(const float* __restrict__ x,
                                                  const float* __restrict__ wgt,
                                                  const float* __restrict__ bias,
                                                  float* __restrict__ partials) {
    __shared__ float red[8];
    const int bid   = blockIdx.x;        // plane*4 + q
    const int q     = bid & 3;
    const int plane = bid >> 2;          // n*64 + c
    const int c     = plane & 63;
    const int n     = plane >> 6;
    const int t     = threadIdx.x;
    const int cg    = t & 31, rg = t >> 5;
    const int w4    = cg * 4, r0 = q * 32 + rg * 4;
    const bool hasL = (cg != 0), hasR = (cg != 31);

    float W[9];
#pragma unroll
    for (int k = 0; k < 9; ++k) W[k] = wgt[c * 9 + k];
    const float bv = bias[c];
    const float* bp = x + (size_t)plane * PLANE;

    float v[6][6];
    load_win(bp, r0, w4, hasL, hasR, v);

    float sum = 0.f, sq = 0.f;
#pragma unroll
    for (int k = 0; k < 4; ++k) {
        float acc[4];
        conv_row(v[k], v[k + 1], v[k + 2], W, bv, acc);
#pragma unroll
        for (int j = 0; j < 4; ++j) {
            sum += acc[j];
            sq = fmaf(acc[j], acc[j], sq);
        }
    }

#pragma unroll
    for (int off = 32; off; off >>= 1) {
        sum += __shfl_down(sum, off);
        sq  += __shfl_down(sq, off);
    }
    const int wave = t >> 6, lane = t & 63;
    if (lane == 0) { red[wave] = sum; red[4 + wave] = sq; }
    __syncthreads();
    if (t == 0) {
        const int pi = n * 4 + q;        // 0..127
        partials[c * 128 + pi]         = red[0] + red[1] + red[2] + red[3];
        partials[NPART + c * 128 + pi] = red[4] + red[5] + red[6] + red[7];
    }
}

// ---------------- pass 2: recompute conv, normalize, relu, store ----------------
__global__ __launch_bounds__(256) void pass_apply(const float* __restrict__ x,
                                                  const float* __restrict__ wgt,
                                                  const float* __restrict__ bias,
                                                  const float* __restrict__ partials,
                                                  const float* __restrict__ gamma,
                                                  const float* __restrict__ beta,
                                                  float* __restrict__ out) {
    const int bid   = blockIdx.x;
    const int q     = bid & 3;
    const int plane = bid >> 2;
    const int c     = plane & 63;
    const int t     = threadIdx.x;
    const int cg    = t & 31, rg = t >> 5;
    const int w4    = cg * 4, r0 = q * 32 + rg * 4;
    const bool hasL = (cg != 0), hasR = (cg != 31);

    float W[9];
#pragma unroll
    for (int k = 0; k < 9; ++k) W[k] = wgt[c * 9 + k];
    const float bv = bias[c];
    const float* bp = x + (size_t)plane * PLANE;

    // issue the 18 x-loads first; stats fold hides underneath
    float v[6][6];
    load_win(bp, r0, w4, hasL, hasR, v);

    // wave-local stats fold: 128 partials per channel, coalesced, no LDS/barrier
    const int lane = t & 63;
    float S = partials[c * 128 + lane]         + partials[c * 128 + 64 + lane];
    float Q = partials[NPART + c * 128 + lane] + partials[NPART + c * 128 + 64 + lane];
#pragma unroll
    for (int off = 32; off; off >>= 1) {
        S += __shfl_xor(S, off);
        Q += __shfl_xor(Q, off);
    }
    const float mean = S * COUNT_INV;
    const float var  = fmaxf(Q * COUNT_INV - mean * mean, 0.f);
    const float s    = gamma[c] * rsqrtf(var + EPSV);
    const float sh   = fmaf(bv, s, beta[c] - mean * s);

    float* op = out + (size_t)plane * PLANE;
#pragma unroll
    for (int k = 0; k < 4; ++k) {
        float acc[4];
        conv_row(v[k], v[k + 1], v[k + 2], W, 0.f, acc);
        f4v o;
        o.x = fmaxf(fmaf(acc[0], s, sh), 0.f);
        o.y = fmaxf(fmaf(acc[1], s, sh), 0.f);
        o.z = fmaxf(fmaf(acc[2], s, sh), 0.f);
        o.w = fmaxf(fmaf(acc[3], s, sh), 0.f);
        __builtin_nontemporal_store(o, (f4v*)(op + (r0 + k) * HW + w4));
    }
}

extern "C" void kernel_launch(void* const* d_in, const int* in_sizes, int n_in,
                              void* d_out, int out_size, void* d_ws, size_t ws_size,
                              hipStream_t stream) {
    const float* x     = (const float*)d_in[0];
    const float* w     = (const float*)d_in[1];
    const float* b     = (const float*)d_in[2];
    const float* gamma = (const float*)d_in[3];
    const float* beta  = (const float*)d_in[4];
    float* out = (float*)d_out;
    float* ws  = (float*)d_ws;

    pass_stats<<<NB * NCH * NQ, 256, 0, stream>>>(x, w, b, ws);
    pass_apply<<<NB * NCH * NQ, 256, 0, stream>>>(x, w, b, ws, gamma, beta, out);
}

// Round 5
// 73.040 us; speedup vs baseline: 1.1873x; 1.0271x over previous
//
#include <hip/hip_runtime.h>

#define HW        128
#define PLANE     16384            // 128*128
#define NCH       64
#define NB        32
#define NQ        4                // quarter-planes (32 rows each)
#define NPART     8192             // NB*NCH*NQ partials per array
#define COUNT_INV (1.0f / 524288.0f)
#define EPSV      1e-5f

#define YELEMS    (NB * NCH * PLANE)            // 33,554,432
#define PART_OFF  (YELEMS / 2)                  // float index of partials in ws
#define WS_NEED   ((size_t)YELEMS * 2 + 16384 * 4)

typedef float    f4v __attribute__((ext_vector_type(4)));
typedef _Float16 h4v __attribute__((ext_vector_type(4)));

// ws layout:
//   bytes [0 .. 67108863]           y as fp16 (NCHW, same indexing as x)
//   floats[PART_OFF .. +8191]       per-quarter sum,   idx = c*128 + (n*4+q)
//   floats[PART_OFF+8192 .. +16383] per-quarter sumsq, same layout

__device__ __forceinline__ void load_win(const float* __restrict__ bp, int r0, int w4,
                                         bool hasL, bool hasR, float (&v)[6][6]) {
#pragma unroll
    for (int i = 0; i < 6; ++i) {
        int g = r0 - 1 + i;
        if ((unsigned)g < (unsigned)HW) {
            const float* rp = bp + g * HW + w4;
            float4 m = *(const float4*)rp;
            v[i][0] = hasL ? rp[-1] : 0.f;
            v[i][1] = m.x; v[i][2] = m.y; v[i][3] = m.z; v[i][4] = m.w;
            v[i][5] = hasR ? rp[4] : 0.f;
        } else {
#pragma unroll
            for (int j = 0; j < 6; ++j) v[i][j] = 0.f;
        }
    }
}

__device__ __forceinline__ void conv_row(const float (&tp)[6], const float (&md)[6],
                                         const float (&bt)[6], const float* W,
                                         float bias, float (&acc)[4]) {
#pragma unroll
    for (int j = 0; j < 4; ++j) {
        float a = bias;
        a = fmaf(tp[j],     W[0], a);
        a = fmaf(tp[j + 1], W[1], a);
        a = fmaf(tp[j + 2], W[2], a);
        a = fmaf(md[j],     W[3], a);
        a = fmaf(md[j + 1], W[4], a);
        a = fmaf(md[j + 2], W[5], a);
        a = fmaf(bt[j],     W[6], a);
        a = fmaf(bt[j + 1], W[7], a);
        a = fmaf(bt[j + 2], W[8], a);
        acc[j] = a;
    }
}

// ---------- pass 1: conv -> y(fp16) + per-quarter sum/sumsq ----------
__global__ __launch_bounds__(256) void pass_conv_stats(const float* __restrict__ x,
                                                       const float* __restrict__ wgt,
                                                       const float* __restrict__ bias,
                                                       _Float16* __restrict__ yh,
                                                       float* __restrict__ partials) {
    __shared__ float red[8];
    const int bid   = blockIdx.x;        // plane*4 + q
    const int q     = bid & 3;
    const int plane = bid >> 2;          // n*64 + c
    const int c     = plane & 63;
    const int n     = plane >> 6;
    const int t     = threadIdx.x;
    const int cg    = t & 31, rg = t >> 5;
    const int w4    = cg * 4, r0 = q * 32 + rg * 4;
    const bool hasL = (cg != 0), hasR = (cg != 31);

    float W[9];
#pragma unroll
    for (int k = 0; k < 9; ++k) W[k] = wgt[c * 9 + k];
    const float bv = bias[c];
    const float* bp = x + (size_t)plane * PLANE;
    _Float16* yp = yh + (size_t)plane * PLANE;

    float v[6][6];
    load_win(bp, r0, w4, hasL, hasR, v);

    float sum = 0.f, sq = 0.f;
#pragma unroll
    for (int k = 0; k < 4; ++k) {
        float acc[4];
        conv_row(v[k], v[k + 1], v[k + 2], W, bv, acc);
        h4v hv;
        hv.x = (_Float16)acc[0]; hv.y = (_Float16)acc[1];
        hv.z = (_Float16)acc[2]; hv.w = (_Float16)acc[3];
        *(h4v*)(yp + (r0 + k) * HW + w4) = hv;   // keep cached (L2/L3) for pass 2
#pragma unroll
        for (int j = 0; j < 4; ++j) {
            sum += acc[j];
            sq = fmaf(acc[j], acc[j], sq);
        }
    }

#pragma unroll
    for (int off = 32; off; off >>= 1) {
        sum += __shfl_down(sum, off);
        sq  += __shfl_down(sq, off);
    }
    const int wave = t >> 6, lane = t & 63;
    if (lane == 0) { red[wave] = sum; red[4 + wave] = sq; }
    __syncthreads();
    if (t == 0) {
        const int pi = n * 4 + q;        // 0..127
        partials[c * 128 + pi]         = red[0] + red[1] + red[2] + red[3];
        partials[NPART + c * 128 + pi] = red[4] + red[5] + red[6] + red[7];
    }
}

// ---------- pass 2: elementwise normalize + relu from y(fp16) ----------
__global__ __launch_bounds__(256) void pass_norm(const _Float16* __restrict__ yh,
                                                 const float* __restrict__ partials,
                                                 const float* __restrict__ gamma,
                                                 const float* __restrict__ beta,
                                                 float* __restrict__ out) {
    const int bid   = blockIdx.x;        // plane*4 + q
    const int q     = bid & 3;
    const int plane = bid >> 2;
    const int c     = plane & 63;
    const int t     = threadIdx.x;
    const int cg    = t & 31, rg = t >> 5;
    const int w4    = cg * 4, r0 = q * 32 + rg * 4;

    const _Float16* yp = yh + (size_t)plane * PLANE;

    // issue the 4 y-loads up front; stats fold hides underneath
    h4v hv[4];
#pragma unroll
    for (int k = 0; k < 4; ++k)
        hv[k] = *(const h4v*)(yp + (r0 + k) * HW + w4);

    // wave-local stats fold: 128 partials per channel, coalesced, no LDS/barrier
    const int lane = t & 63;
    float S = partials[c * 128 + lane]         + partials[c * 128 + 64 + lane];
    float Q = partials[NPART + c * 128 + lane] + partials[NPART + c * 128 + 64 + lane];
#pragma unroll
    for (int off = 32; off; off >>= 1) {
        S += __shfl_xor(S, off);
        Q += __shfl_xor(Q, off);
    }
    const float mean = S * COUNT_INV;
    const float var  = fmaxf(Q * COUNT_INV - mean * mean, 0.f);
    const float s    = gamma[c] * rsqrtf(var + EPSV);
    const float sh   = beta[c] - mean * s;

    float* op = out + (size_t)plane * PLANE;
#pragma unroll
    for (int k = 0; k < 4; ++k) {
        f4v o;
        o.x = fmaxf(fmaf((float)hv[k].x, s, sh), 0.f);
        o.y = fmaxf(fmaf((float)hv[k].y, s, sh), 0.f);
        o.z = fmaxf(fmaf((float)hv[k].z, s, sh), 0.f);
        o.w = fmaxf(fmaf((float)hv[k].w, s, sh), 0.f);
        __builtin_nontemporal_store(o, (f4v*)(op + (r0 + k) * HW + w4));
    }
}

// ---------------- fallback (round-4 path, no y buffer) ----------------
__global__ __launch_bounds__(256) void pass_stats_fb(const float* __restrict__ x,
                                                     const float* __restrict__ wgt,
                                                     const float* __restrict__ bias,
                                                     float* __restrict__ partials) {
    __shared__ float red[8];
    const int bid   = blockIdx.x;
    const int q     = bid & 3;
    const int plane = bid >> 2;
    const int c     = plane & 63;
    const int n     = plane >> 6;
    const int t     = threadIdx.x;
    const int cg    = t & 31, rg = t >> 5;
    const int w4    = cg * 4, r0 = q * 32 + rg * 4;
    const bool hasL = (cg != 0), hasR = (cg != 31);

    float W[9];
#pragma unroll
    for (int k = 0; k < 9; ++k) W[k] = wgt[c * 9 + k];
    const float bv = bias[c];
    const float* bp = x + (size_t)plane * PLANE;

    float v[6][6];
    load_win(bp, r0, w4, hasL, hasR, v);

    float sum = 0.f, sq = 0.f;
#pragma unroll
    for (int k = 0; k < 4; ++k) {
        float acc[4];
        conv_row(v[k], v[k + 1], v[k + 2], W, bv, acc);
#pragma unroll
        for (int j = 0; j < 4; ++j) { sum += acc[j]; sq = fmaf(acc[j], acc[j], sq); }
    }
#pragma unroll
    for (int off = 32; off; off >>= 1) {
        sum += __shfl_down(sum, off);
        sq  += __shfl_down(sq, off);
    }
    const int wave = t >> 6, lane = t & 63;
    if (lane == 0) { red[wave] = sum; red[4 + wave] = sq; }
    __syncthreads();
    if (t == 0) {
        const int pi = n * 4 + q;
        partials[c * 128 + pi]         = red[0] + red[1] + red[2] + red[3];
        partials[NPART + c * 128 + pi] = red[4] + red[5] + red[6] + red[7];
    }
}

__global__ __launch_bounds__(256) void pass_apply_fb(const float* __restrict__ x,
                                                     const float* __restrict__ wgt,
                                                     const float* __restrict__ bias,
                                                     const float* __restrict__ partials,
                                                     const float* __restrict__ gamma,
                                                     const float* __restrict__ beta,
                                                     float* __restrict__ out) {
    const int bid   = blockIdx.x;
    const int q     = bid & 3;
    const int plane = bid >> 2;
    const int c     = plane & 63;
    const int t     = threadIdx.x;
    const int cg    = t & 31, rg = t >> 5;
    const int w4    = cg * 4, r0 = q * 32 + rg * 4;
    const bool hasL = (cg != 0), hasR = (cg != 31);

    float W[9];
#pragma unroll
    for (int k = 0; k < 9; ++k) W[k] = wgt[c * 9 + k];
    const float bv = bias[c];
    const float* bp = x + (size_t)plane * PLANE;

    float v[6][6];
    load_win(bp, r0, w4, hasL, hasR, v);

    const int lane = t & 63;
    float S = partials[c * 128 + lane]         + partials[c * 128 + 64 + lane];
    float Q = partials[NPART + c * 128 + lane] + partials[NPART + c * 128 + 64 + lane];
#pragma unroll
    for (int off = 32; off; off >>= 1) {
        S += __shfl_xor(S, off);
        Q += __shfl_xor(Q, off);
    }
    const float mean = S * COUNT_INV;
    const float var  = fmaxf(Q * COUNT_INV - mean * mean, 0.f);
    const float s    = gamma[c] * rsqrtf(var + EPSV);
    const float sh   = fmaf(bv, s, beta[c] - mean * s);

    float* op = out + (size_t)plane * PLANE;
#pragma unroll
    for (int k = 0; k < 4; ++k) {
        float acc[4];
        conv_row(v[k], v[k + 1], v[k + 2], W, 0.f, acc);
        f4v o;
        o.x = fmaxf(fmaf(acc[0], s, sh), 0.f);
        o.y = fmaxf(fmaf(acc[1], s, sh), 0.f);
        o.z = fmaxf(fmaf(acc[2], s, sh), 0.f);
        o.w = fmaxf(fmaf(acc[3], s, sh), 0.f);
        __builtin_nontemporal_store(o, (f4v*)(op + (r0 + k) * HW + w4));
    }
}

extern "C" void kernel_launch(void* const* d_in, const int* in_sizes, int n_in,
                              void* d_out, int out_size, void* d_ws, size_t ws_size,
                              hipStream_t stream) {
    const float* x     = (const float*)d_in[0];
    const float* w     = (const float*)d_in[1];
    const float* b     = (const float*)d_in[2];
    const float* gamma = (const float*)d_in[3];
    const float* beta  = (const float*)d_in[4];
    float* out = (float*)d_out;

    if (ws_size >= WS_NEED) {
        _Float16* yh  = (_Float16*)d_ws;
        float* parts  = (float*)d_ws + PART_OFF;
        pass_conv_stats<<<NB * NCH * NQ, 256, 0, stream>>>(x, w, b, yh, parts);
        pass_norm<<<NB * NCH * NQ, 256, 0, stream>>>(yh, parts, gamma, beta, out);
    } else {
        float* parts = (float*)d_ws;
        pass_stats_fb<<<NB * NCH * NQ, 256, 0, stream>>>(x, w, b, parts);
        pass_apply_fb<<<NB * NCH * NQ, 256, 0, stream>>>(x, w, b, parts, gamma, beta, out);
    }
}

// Round 6
// 73.026 us; speedup vs baseline: 1.1875x; 1.0002x over previous
//
#include <hip/hip_runtime.h>
#include <hip/hip_cooperative_groups.h>

namespace cg = cooperative_groups;

#define HW        128
#define PLANE     16384            // 128*128
#define NCH       64
#define NB        32
#define NQ        4
#define NPART     8192             // fallback partial count
#define COUNT_INV (1.0f / 524288.0f)
#define EPSV      1e-5f

#define YELEMS    (NB * NCH * PLANE)
#define PART_OFF  (YELEMS / 2)
#define WS_NEED   ((size_t)YELEMS * 2 + 16384 * 4)

typedef float    f4v __attribute__((ext_vector_type(4)));
typedef _Float16 h2v __attribute__((ext_vector_type(2)));
typedef _Float16 h4v __attribute__((ext_vector_type(4)));

__device__ __forceinline__ void load_win(const float* __restrict__ bp, int r0, int w4,
                                         bool hasL, bool hasR, float (&v)[6][6]) {
#pragma unroll
    for (int i = 0; i < 6; ++i) {
        int g = r0 - 1 + i;
        if ((unsigned)g < (unsigned)HW) {
            const float* rp = bp + g * HW + w4;
            float4 m = *(const float4*)rp;
            v[i][0] = hasL ? rp[-1] : 0.f;
            v[i][1] = m.x; v[i][2] = m.y; v[i][3] = m.z; v[i][4] = m.w;
            v[i][5] = hasR ? rp[4] : 0.f;
        } else {
#pragma unroll
            for (int j = 0; j < 6; ++j) v[i][j] = 0.f;
        }
    }
}

__device__ __forceinline__ void conv_row(const float (&tp)[6], const float (&md)[6],
                                         const float (&bt)[6], const float* W,
                                         float bias, float (&acc)[4]) {
#pragma unroll
    for (int j = 0; j < 4; ++j) {
        float a = bias;
        a = fmaf(tp[j],     W[0], a);
        a = fmaf(tp[j + 1], W[1], a);
        a = fmaf(tp[j + 2], W[2], a);
        a = fmaf(md[j],     W[3], a);
        a = fmaf(md[j + 1], W[4], a);
        a = fmaf(md[j + 2], W[5], a);
        a = fmaf(bt[j],     W[6], a);
        a = fmaf(bt[j + 1], W[7], a);
        a = fmaf(bt[j + 2], W[8], a);
        acc[j] = a;
    }
}

// ---------------- fused cooperative kernel: y lives in registers ----------------
// 1024 blocks x 256 threads; block bid handles planes (2*(bid>>6)+pp)*64 + (bid&63).
// ws: [0..2047] per-plane sum (idx c*32+n), [2048..4095] per-plane sumsq.
__global__ __launch_bounds__(256, 4) void fused(const float* __restrict__ x,
                                                const float* __restrict__ wgt,
                                                const float* __restrict__ bias,
                                                const float* __restrict__ gamma,
                                                const float* __restrict__ beta,
                                                float* __restrict__ partials,
                                                float* __restrict__ out) {
    __shared__ float red[8];
    __shared__ float ssh[2];
    const int bid = blockIdx.x;
    const int c   = bid & 63;
    const int np  = bid >> 6;          // 0..15
    const int t   = threadIdx.x;
    const int cg_ = t & 31, rg = t >> 5;
    const int w4  = cg_ * 4;
    const bool hasL = (cg_ != 0), hasR = (cg_ != 31);

    float W[9];
#pragma unroll
    for (int k = 0; k < 9; ++k) W[k] = wgt[c * 9 + k];
    const float bv = bias[c];

    h2v yr0[32];   // plane 0: 64 outputs packed
    h2v yr1[32];   // plane 1

    // ---- phase 1: conv, keep y in regs, per-plane stats ----
#pragma unroll
    for (int pp = 0; pp < 2; ++pp) {
        const int n = np * 2 + pp;
        const int plane = n * NCH + c;
        const float* bp = x + (size_t)plane * PLANE;
        h2v* yr = pp ? yr1 : yr0;

        float sum = 0.f, sq = 0.f;
#pragma unroll
        for (int k = 0; k < 4; ++k) {           // 4 patches of 4 rows
            const int r0 = rg * 16 + k * 4;
            float v[6][6];
            load_win(bp, r0, w4, hasL, hasR, v);
#pragma unroll
            for (int rr = 0; rr < 4; ++rr) {
                float acc[4];
                conv_row(v[rr], v[rr + 1], v[rr + 2], W, bv, acc);
                h2v a, b;
                a.x = (_Float16)acc[0]; a.y = (_Float16)acc[1];
                b.x = (_Float16)acc[2]; b.y = (_Float16)acc[3];
                yr[k * 8 + rr * 2]     = a;
                yr[k * 8 + rr * 2 + 1] = b;
#pragma unroll
                for (int j = 0; j < 4; ++j) {
                    sum += acc[j];
                    sq = fmaf(acc[j], acc[j], sq);
                }
            }
        }
#pragma unroll
        for (int off = 32; off; off >>= 1) {
            sum += __shfl_down(sum, off);
            sq  += __shfl_down(sq, off);
        }
        const int wave = t >> 6, lane = t & 63;
        if (lane == 0) { red[wave] = sum; red[4 + wave] = sq; }
        __syncthreads();
        if (t == 0) {
            partials[c * 32 + n]        = red[0] + red[1] + red[2] + red[3];
            partials[2048 + c * 32 + n] = red[4] + red[5] + red[6] + red[7];
        }
        __syncthreads();
    }

    __threadfence();
    cg::this_grid().sync();

    // ---- stats fold: 32 lanes, coalesced ----
    if (t < 32) {
        float S = partials[c * 32 + t];
        float Q = partials[2048 + c * 32 + t];
#pragma unroll
        for (int off = 16; off; off >>= 1) {
            S += __shfl_xor(S, off);
            Q += __shfl_xor(Q, off);
        }
        if (t == 0) {
            float mean = S * COUNT_INV;
            float var  = fmaxf(Q * COUNT_INV - mean * mean, 0.f);
            float s    = gamma[c] * rsqrtf(var + EPSV);
            ssh[0] = s;
            ssh[1] = beta[c] - mean * s;   // bias already inside y
        }
    }
    __syncthreads();
    const float s  = ssh[0];
    const float sh = ssh[1];

    // ---- phase 2: unpack regs, normalize, relu, store ----
#pragma unroll
    for (int pp = 0; pp < 2; ++pp) {
        const int n = np * 2 + pp;
        const int plane = n * NCH + c;
        float* op = out + (size_t)plane * PLANE;
        h2v* yr = pp ? yr1 : yr0;
#pragma unroll
        for (int k = 0; k < 4; ++k) {
#pragma unroll
            for (int rr = 0; rr < 4; ++rr) {
                h2v a = yr[k * 8 + rr * 2];
                h2v b = yr[k * 8 + rr * 2 + 1];
                f4v o;
                o.x = fmaxf(fmaf((float)a.x, s, sh), 0.f);
                o.y = fmaxf(fmaf((float)a.y, s, sh), 0.f);
                o.z = fmaxf(fmaf((float)b.x, s, sh), 0.f);
                o.w = fmaxf(fmaf((float)b.y, s, sh), 0.f);
                const int row = rg * 16 + k * 4 + rr;
                __builtin_nontemporal_store(o, (f4v*)(op + row * HW + w4));
            }
        }
    }
}

// ---------------- fallback: round-5 two-pass (fp16 y staging) ----------------
__global__ __launch_bounds__(256) void pass_conv_stats(const float* __restrict__ x,
                                                       const float* __restrict__ wgt,
                                                       const float* __restrict__ bias,
                                                       _Float16* __restrict__ yh,
                                                       float* __restrict__ partials) {
    __shared__ float red[8];
    const int bid   = blockIdx.x;
    const int q     = bid & 3;
    const int plane = bid >> 2;
    const int c     = plane & 63;
    const int n     = plane >> 6;
    const int t     = threadIdx.x;
    const int cg    = t & 31, rg = t >> 5;
    const int w4    = cg * 4, r0 = q * 32 + rg * 4;
    const bool hasL = (cg != 0), hasR = (cg != 31);

    float W[9];
#pragma unroll
    for (int k = 0; k < 9; ++k) W[k] = wgt[c * 9 + k];
    const float bv = bias[c];
    const float* bp = x + (size_t)plane * PLANE;
    _Float16* yp = yh + (size_t)plane * PLANE;

    float v[6][6];
    load_win(bp, r0, w4, hasL, hasR, v);

    float sum = 0.f, sq = 0.f;
#pragma unroll
    for (int k = 0; k < 4; ++k) {
        float acc[4];
        conv_row(v[k], v[k + 1], v[k + 2], W, bv, acc);
        h4v hv;
        hv.x = (_Float16)acc[0]; hv.y = (_Float16)acc[1];
        hv.z = (_Float16)acc[2]; hv.w = (_Float16)acc[3];
        *(h4v*)(yp + (r0 + k) * HW + w4) = hv;
#pragma unroll
        for (int j = 0; j < 4; ++j) { sum += acc[j]; sq = fmaf(acc[j], acc[j], sq); }
    }
#pragma unroll
    for (int off = 32; off; off >>= 1) {
        sum += __shfl_down(sum, off);
        sq  += __shfl_down(sq, off);
    }
    const int wave = t >> 6, lane = t & 63;
    if (lane == 0) { red[wave] = sum; red[4 + wave] = sq; }
    __syncthreads();
    if (t == 0) {
        const int pi = n * 4 + q;
        partials[c * 128 + pi]         = red[0] + red[1] + red[2] + red[3];
        partials[NPART + c * 128 + pi] = red[4] + red[5] + red[6] + red[7];
    }
}

__global__ __launch_bounds__(256) void pass_norm(const _Float16* __restrict__ yh,
                                                 const float* __restrict__ partials,
                                                 const float* __restrict__ gamma,
                                                 const float* __restrict__ beta,
                                                 float* __restrict__ out) {
    const int bid   = blockIdx.x;
    const int q     = bid & 3;
    const int plane = bid >> 2;
    const int c     = plane & 63;
    const int t     = threadIdx.x;
    const int cg    = t & 31, rg = t >> 5;
    const int w4    = cg * 4, r0 = q * 32 + rg * 4;

    const _Float16* yp = yh + (size_t)plane * PLANE;
    h4v hv[4];
#pragma unroll
    for (int k = 0; k < 4; ++k)
        hv[k] = *(const h4v*)(yp + (r0 + k) * HW + w4);

    const int lane = t & 63;
    float S = partials[c * 128 + lane]         + partials[c * 128 + 64 + lane];
    float Q = partials[NPART + c * 128 + lane] + partials[NPART + c * 128 + 64 + lane];
#pragma unroll
    for (int off = 32; off; off >>= 1) {
        S += __shfl_xor(S, off);
        Q += __shfl_xor(Q, off);
    }
    const float mean = S * COUNT_INV;
    const float var  = fmaxf(Q * COUNT_INV - mean * mean, 0.f);
    const float s    = gamma[c] * rsqrtf(var + EPSV);
    const float sh   = beta[c] - mean * s;

    float* op = out + (size_t)plane * PLANE;
#pragma unroll
    for (int k = 0; k < 4; ++k) {
        f4v o;
        o.x = fmaxf(fmaf((float)hv[k].x, s, sh), 0.f);
        o.y = fmaxf(fmaf((float)hv[k].y, s, sh), 0.f);
        o.z = fmaxf(fmaf((float)hv[k].z, s, sh), 0.f);
        o.w = fmaxf(fmaf((float)hv[k].w, s, sh), 0.f);
        __builtin_nontemporal_store(o, (f4v*)(op + (r0 + k) * HW + w4));
    }
}

extern "C" void kernel_launch(void* const* d_in, const int* in_sizes, int n_in,
                              void* d_out, int out_size, void* d_ws, size_t ws_size,
                              hipStream_t stream) {
    const float* x     = (const float*)d_in[0];
    const float* w     = (const float*)d_in[1];
    const float* b     = (const float*)d_in[2];
    const float* gamma = (const float*)d_in[3];
    const float* beta  = (const float*)d_in[4];
    float* out = (float*)d_out;

    int nb = 0;
    hipError_t qe = hipOccupancyMaxActiveBlocksPerMultiprocessor(
        &nb, reinterpret_cast<const void*>(fused), 256, 0);

    if (qe == hipSuccess && nb >= 4) {
        float* parts = (float*)d_ws;
        const float* xa = x; const float* wa = w; const float* ba = b;
        const float* ga = gamma; const float* be = beta;
        float* pw = parts; float* oa = out;
        void* args[] = {&xa, &wa, &ba, &ga, &be, &pw, &oa};
        hipLaunchCooperativeKernel(reinterpret_cast<const void*>(fused),
                                   dim3(1024), dim3(256), args, 0, stream);
    } else if (ws_size >= WS_NEED) {
        _Float16* yh  = (_Float16*)d_ws;
        float* parts  = (float*)d_ws + PART_OFF;
        pass_conv_stats<<<NB * NCH * NQ, 256, 0, stream>>>(x, w, b, yh, parts);
        pass_norm<<<NB * NCH * NQ, 256, 0, stream>>>(yh, parts, gamma, beta, out);
    }
}

// Round 7
// 72.936 us; speedup vs baseline: 1.1890x; 1.0012x over previous
//
#include <hip/hip_runtime.h>
#include <hip/hip_cooperative_groups.h>

namespace cg = cooperative_groups;

#define HW        128
#define PLANE     16384            // 128*128
#define NCH       64
#define NB        32
#define NQ        4
#define NPART     8192             // fallback partial count
#define COUNT_INV (1.0f / 524288.0f)
#define EPSV      1e-5f

#define YELEMS    (NB * NCH * PLANE)
#define PART_OFF  (YELEMS / 2)
#define WS_NEED   ((size_t)YELEMS * 2 + 16384 * 4)

typedef float    f4v __attribute__((ext_vector_type(4)));
typedef _Float16 h2v __attribute__((ext_vector_type(2)));
typedef _Float16 h4v __attribute__((ext_vector_type(4)));

__device__ __forceinline__ void load_win(const float* __restrict__ bp, int r0, int w4,
                                         bool hasL, bool hasR, float (&v)[6][6]) {
#pragma unroll
    for (int i = 0; i < 6; ++i) {
        int g = r0 - 1 + i;
        if ((unsigned)g < (unsigned)HW) {
            const float* rp = bp + g * HW + w4;
            float4 m = *(const float4*)rp;
            v[i][0] = hasL ? rp[-1] : 0.f;
            v[i][1] = m.x; v[i][2] = m.y; v[i][3] = m.z; v[i][4] = m.w;
            v[i][5] = hasR ? rp[4] : 0.f;
        } else {
#pragma unroll
            for (int j = 0; j < 6; ++j) v[i][j] = 0.f;
        }
    }
}

__device__ __forceinline__ void conv_row(const float (&tp)[6], const float (&md)[6],
                                         const float (&bt)[6], const float* W,
                                         float bias, float (&acc)[4]) {
#pragma unroll
    for (int j = 0; j < 4; ++j) {
        float a = bias;
        a = fmaf(tp[j],     W[0], a);
        a = fmaf(tp[j + 1], W[1], a);
        a = fmaf(tp[j + 2], W[2], a);
        a = fmaf(md[j],     W[3], a);
        a = fmaf(md[j + 1], W[4], a);
        a = fmaf(md[j + 2], W[5], a);
        a = fmaf(bt[j],     W[6], a);
        a = fmaf(bt[j + 1], W[7], a);
        a = fmaf(bt[j + 2], W[8], a);
        acc[j] = a;
    }
}

// ---------------- fused cooperative kernel: y truly in registers ----------------
// 1024 blocks x 256 threads; block bid: planes (2*(bid>>6)+pp)*64 + (bid&63).
// y[64] is a single flat register array; ALL indices compile-time constants
// (no pointer-select between arrays -> no SROA defeat -> no scratch).
// ws: [0..2047] per-plane sum (idx c*32+n), [2048..4095] per-plane sumsq.
__global__ __launch_bounds__(256, 4) void fused(const float* __restrict__ x,
                                                const float* __restrict__ wgt,
                                                const float* __restrict__ bias,
                                                const float* __restrict__ gamma,
                                                const float* __restrict__ beta,
                                                float* __restrict__ partials,
                                                float* __restrict__ out) {
    __shared__ float red[8];
    __shared__ float ssh[2];
    const int bid = blockIdx.x;
    const int c   = bid & 63;
    const int np  = bid >> 6;          // 0..15
    const int t   = threadIdx.x;
    const int cg_ = t & 31, rg = t >> 5;
    const int w4  = cg_ * 4;
    const bool hasL = (cg_ != 0), hasR = (cg_ != 31);

    float W[9];
#pragma unroll
    for (int k = 0; k < 9; ++k) W[k] = wgt[c * 9 + k];
    const float bv = bias[c];

    h2v y[64];                          // 2 planes x 64 outputs, packed fp16

    // ---- phase 1: conv, keep y in regs, per-plane stats ----
#pragma unroll
    for (int pp = 0; pp < 2; ++pp) {
        const int n = np * 2 + pp;
        const int plane = n * NCH + c;
        const float* bp = x + (size_t)plane * PLANE;

        float sum = 0.f, sq = 0.f;
#pragma unroll
        for (int k = 0; k < 4; ++k) {           // 4 patches of 4 rows
            const int r0 = rg * 16 + k * 4;
            float v[6][6];
            load_win(bp, r0, w4, hasL, hasR, v);
#pragma unroll
            for (int rr = 0; rr < 4; ++rr) {
                float acc[4];
                conv_row(v[rr], v[rr + 1], v[rr + 2], W, bv, acc);
                h2v a, b2;
                a.x  = (_Float16)acc[0]; a.y  = (_Float16)acc[1];
                b2.x = (_Float16)acc[2]; b2.y = (_Float16)acc[3];
                y[pp * 32 + k * 8 + rr * 2]     = a;
                y[pp * 32 + k * 8 + rr * 2 + 1] = b2;
#pragma unroll
                for (int j = 0; j < 4; ++j) {
                    sum += acc[j];
                    sq = fmaf(acc[j], acc[j], sq);
                }
            }
        }
#pragma unroll
        for (int off = 32; off; off >>= 1) {
            sum += __shfl_down(sum, off);
            sq  += __shfl_down(sq, off);
        }
        const int wave = t >> 6, lane = t & 63;
        if (lane == 0) { red[wave] = sum; red[4 + wave] = sq; }
        __syncthreads();
        if (t == 0) {
            partials[c * 32 + n]        = red[0] + red[1] + red[2] + red[3];
            partials[2048 + c * 32 + n] = red[4] + red[5] + red[6] + red[7];
        }
        __syncthreads();
    }

    __threadfence();
    cg::this_grid().sync();

    // ---- stats fold: 32 lanes, coalesced ----
    if (t < 32) {
        float S = partials[c * 32 + t];
        float Q = partials[2048 + c * 32 + t];
#pragma unroll
        for (int off = 16; off; off >>= 1) {
            S += __shfl_xor(S, off);
            Q += __shfl_xor(Q, off);
        }
        if (t == 0) {
            float mean = S * COUNT_INV;
            float var  = fmaxf(Q * COUNT_INV - mean * mean, 0.f);
            float s    = gamma[c] * rsqrtf(var + EPSV);
            ssh[0] = s;
            ssh[1] = beta[c] - mean * s;   // bias already inside y
        }
    }
    __syncthreads();
    const float s  = ssh[0];
    const float sh = ssh[1];

    // ---- phase 2: unpack regs, normalize, relu, store ----
#pragma unroll
    for (int pp = 0; pp < 2; ++pp) {
        const int plane = (np * 2 + pp) * NCH + c;
        float* op = out + (size_t)plane * PLANE;
#pragma unroll
        for (int k = 0; k < 4; ++k) {
#pragma unroll
            for (int rr = 0; rr < 4; ++rr) {
                h2v a  = y[pp * 32 + k * 8 + rr * 2];
                h2v b2 = y[pp * 32 + k * 8 + rr * 2 + 1];
                f4v o;
                o.x = fmaxf(fmaf((float)a.x,  s, sh), 0.f);
                o.y = fmaxf(fmaf((float)a.y,  s, sh), 0.f);
                o.z = fmaxf(fmaf((float)b2.x, s, sh), 0.f);
                o.w = fmaxf(fmaf((float)b2.y, s, sh), 0.f);
                const int row = rg * 16 + k * 4 + rr;
                __builtin_nontemporal_store(o, (f4v*)(op + row * HW + w4));
            }
        }
    }
}

// ---------------- fallback: round-5 two-pass (fp16 y staging) ----------------
__global__ __launch_bounds__(256) void pass_conv_stats(const float* __restrict__ x,
                                                       const float* __restrict__ wgt,
                                                       const float* __restrict__ bias,
                                                       _Float16* __restrict__ yh,
                                                       float* __restrict__ partials) {
    __shared__ float red[8];
    const int bid   = blockIdx.x;
    const int q     = bid & 3;
    const int plane = bid >> 2;
    const int c     = plane & 63;
    const int n     = plane >> 6;
    const int t     = threadIdx.x;
    const int cg    = t & 31, rg = t >> 5;
    const int w4    = cg * 4, r0 = q * 32 + rg * 4;
    const bool hasL = (cg != 0), hasR = (cg != 31);

    float W[9];
#pragma unroll
    for (int k = 0; k < 9; ++k) W[k] = wgt[c * 9 + k];
    const float bv = bias[c];
    const float* bp = x + (size_t)plane * PLANE;
    _Float16* yp = yh + (size_t)plane * PLANE;

    float v[6][6];
    load_win(bp, r0, w4, hasL, hasR, v);

    float sum = 0.f, sq = 0.f;
#pragma unroll
    for (int k = 0; k < 4; ++k) {
        float acc[4];
        conv_row(v[k], v[k + 1], v[k + 2], W, bv, acc);
        h4v hv;
        hv.x = (_Float16)acc[0]; hv.y = (_Float16)acc[1];
        hv.z = (_Float16)acc[2]; hv.w = (_Float16)acc[3];
        *(h4v*)(yp + (r0 + k) * HW + w4) = hv;
#pragma unroll
        for (int j = 0; j < 4; ++j) { sum += acc[j]; sq = fmaf(acc[j], acc[j], sq); }
    }
#pragma unroll
    for (int off = 32; off; off >>= 1) {
        sum += __shfl_down(sum, off);
        sq  += __shfl_down(sq, off);
    }
    const int wave = t >> 6, lane = t & 63;
    if (lane == 0) { red[wave] = sum; red[4 + wave] = sq; }
    __syncthreads();
    if (t == 0) {
        const int pi = n * 4 + q;
        partials[c * 128 + pi]         = red[0] + red[1] + red[2] + red[3];
        partials[NPART + c * 128 + pi] = red[4] + red[5] + red[6] + red[7];
    }
}

__global__ __launch_bounds__(256) void pass_norm(const _Float16* __restrict__ yh,
                                                 const float* __restrict__ partials,
                                                 const float* __restrict__ gamma,
                                                 const float* __restrict__ beta,
                                                 float* __restrict__ out) {
    const int bid   = blockIdx.x;
    const int q     = bid & 3;
    const int plane = bid >> 2;
    const int c     = plane & 63;
    const int t     = threadIdx.x;
    const int cg    = t & 31, rg = t >> 5;
    const int w4    = cg * 4, r0 = q * 32 + rg * 4;

    const _Float16* yp = yh + (size_t)plane * PLANE;
    h4v hv[4];
#pragma unroll
    for (int k = 0; k < 4; ++k)
        hv[k] = *(const h4v*)(yp + (r0 + k) * HW + w4);

    const int lane = t & 63;
    float S = partials[c * 128 + lane]         + partials[c * 128 + 64 + lane];
    float Q = partials[NPART + c * 128 + lane] + partials[NPART + c * 128 + 64 + lane];
#pragma unroll
    for (int off = 32; off; off >>= 1) {
        S += __shfl_xor(S, off);
        Q += __shfl_xor(Q, off);
    }
    const float mean = S * COUNT_INV;
    const float var  = fmaxf(Q * COUNT_INV - mean * mean, 0.f);
    const float s    = gamma[c] * rsqrtf(var + EPSV);
    const float sh   = beta[c] - mean * s;

    float* op = out + (size_t)plane * PLANE;
#pragma unroll
    for (int k = 0; k < 4; ++k) {
        f4v o;
        o.x = fmaxf(fmaf((float)hv[k].x, s, sh), 0.f);
        o.y = fmaxf(fmaf((float)hv[k].y, s, sh), 0.f);
        o.z = fmaxf(fmaf((float)hv[k].z, s, sh), 0.f);
        o.w = fmaxf(fmaf((float)hv[k].w, s, sh), 0.f);
        __builtin_nontemporal_store(o, (f4v*)(op + (r0 + k) * HW + w4));
    }
}

extern "C" void kernel_launch(void* const* d_in, const int* in_sizes, int n_in,
                              void* d_out, int out_size, void* d_ws, size_t ws_size,
                              hipStream_t stream) {
    const float* x     = (const float*)d_in[0];
    const float* w     = (const float*)d_in[1];
    const float* b     = (const float*)d_in[2];
    const float* gamma = (const float*)d_in[3];
    const float* beta  = (const float*)d_in[4];
    float* out = (float*)d_out;

    int nb = 0;
    hipError_t qe = hipOccupancyMaxActiveBlocksPerMultiprocessor(
        &nb, reinterpret_cast<const void*>(fused), 256, 0);

    if (qe == hipSuccess && nb >= 4) {
        float* parts = (float*)d_ws;
        const float* xa = x; const float* wa = w; const float* ba = b;
        const float* ga = gamma; const float* be = beta;
        float* pw = parts; float* oa = out;
        void* args[] = {&xa, &wa, &ba, &ga, &be, &pw, &oa};
        hipLaunchCooperativeKernel(reinterpret_cast<const void*>(fused),
                                   dim3(1024), dim3(256), args, 0, stream);
    } else if (ws_size >= WS_NEED) {
        _Float16* yh  = (_Float16*)d_ws;
        float* parts  = (float*)d_ws + PART_OFF;
        pass_conv_stats<<<NB * NCH * NQ, 256, 0, stream>>>(x, w, b, yh, parts);
        pass_norm<<<NB * NCH * NQ, 256, 0, stream>>>(yh, parts, gamma, beta, out);
    }
}

// Round 8
// 72.882 us; speedup vs baseline: 1.1899x; 1.0007x over previous
//
#include <hip/hip_runtime.h>
#include <hip/hip_cooperative_groups.h>

namespace cg = cooperative_groups;

#define HW        128
#define PLANE     16384            // 128*128
#define NCH       64
#define NB        32
#define NQ        4
#define NPART     8192             // fallback partial count
#define COUNT_INV (1.0f / 524288.0f)
#define EPSV      1e-5f

#define YELEMS    (NB * NCH * PLANE)
#define PART_OFF  (YELEMS / 2)
#define WS_NEED   ((size_t)YELEMS * 2 + 16384 * 4)

typedef float    f4v  __attribute__((ext_vector_type(4)));
typedef _Float16 h4v  __attribute__((ext_vector_type(4)));
typedef _Float16 h64v __attribute__((ext_vector_type(64)));

__device__ __forceinline__ void load_win(const float* __restrict__ bp, int r0, int w4,
                                         bool hasL, bool hasR, float (&v)[6][6]) {
#pragma unroll
    for (int i = 0; i < 6; ++i) {
        int g = r0 - 1 + i;
        if ((unsigned)g < (unsigned)HW) {
            const float* rp = bp + g * HW + w4;
            float4 m = *(const float4*)rp;
            v[i][0] = hasL ? rp[-1] : 0.f;
            v[i][1] = m.x; v[i][2] = m.y; v[i][3] = m.z; v[i][4] = m.w;
            v[i][5] = hasR ? rp[4] : 0.f;
        } else {
#pragma unroll
            for (int j = 0; j < 6; ++j) v[i][j] = 0.f;
        }
    }
}

__device__ __forceinline__ void conv_row(const float (&tp)[6], const float (&md)[6],
                                         const float (&bt)[6], const float* W,
                                         float bias, float (&acc)[4]) {
#pragma unroll
    for (int j = 0; j < 4; ++j) {
        float a = bias;
        a = fmaf(tp[j],     W[0], a);
        a = fmaf(tp[j + 1], W[1], a);
        a = fmaf(tp[j + 2], W[2], a);
        a = fmaf(md[j],     W[3], a);
        a = fmaf(md[j + 1], W[4], a);
        a = fmaf(md[j + 2], W[5], a);
        a = fmaf(bt[j],     W[6], a);
        a = fmaf(bt[j + 1], W[7], a);
        a = fmaf(bt[j + 2], W[8], a);
        acc[j] = a;
    }
}

// ---------------- fused cooperative kernel, y in named vector registers ----------
// 512 blocks x 256 threads, __launch_bounds__(256,2) -> 256-VGPR budget,
// 2 blocks/CU co-resident. Block bid: channel c = bid&63, planes n = (bid>>6)*4 + pi.
// Each thread: 4 planes x (4 patches x 4x4 px) = 256 px, y packed fp16 in 4 named
// 64-wide ext-vectors (first-class SSA values -> cannot be a scratch alloca).
// ws: [0..2047] per-plane sum (idx c*32+n), [2048..4095] per-plane sumsq.

#define PHASE1(PI, Y)                                                          \
    {                                                                          \
        const int n     = np4 + (PI);                                          \
        const int plane = n * NCH + c;                                         \
        const float* bp = x + (size_t)plane * PLANE;                           \
        float sum = 0.f, sq = 0.f;                                             \
        _Pragma("unroll")                                                      \
        for (int k = 0; k < 4; ++k) {                                          \
            const int r0 = rg * 16 + k * 4;                                    \
            float v[6][6];                                                     \
            load_win(bp, r0, w4, hasL, hasR, v);                               \
            _Pragma("unroll")                                                  \
            for (int rr = 0; rr < 4; ++rr) {                                   \
                float acc[4];                                                  \
                conv_row(v[rr], v[rr + 1], v[rr + 2], W, bv, acc);             \
                Y[k * 16 + rr * 4 + 0] = (_Float16)acc[0];                     \
                Y[k * 16 + rr * 4 + 1] = (_Float16)acc[1];                     \
                Y[k * 16 + rr * 4 + 2] = (_Float16)acc[2];                     \
                Y[k * 16 + rr * 4 + 3] = (_Float16)acc[3];                     \
                _Pragma("unroll")                                              \
                for (int j = 0; j < 4; ++j) {                                  \
                    sum += acc[j];                                             \
                    sq = fmaf(acc[j], acc[j], sq);                             \
                }                                                              \
            }                                                                  \
        }                                                                      \
        _Pragma("unroll")                                                      \
        for (int off = 32; off; off >>= 1) {                                   \
            sum += __shfl_down(sum, off);                                      \
            sq  += __shfl_down(sq, off);                                       \
        }                                                                      \
        if ((t & 63) == 0) { red[t >> 6] = sum; red[4 + (t >> 6)] = sq; }      \
        __syncthreads();                                                       \
        if (t == 0) {                                                          \
            partials[c * 32 + n]        = red[0] + red[1] + red[2] + red[3];   \
            partials[2048 + c * 32 + n] = red[4] + red[5] + red[6] + red[7];   \
        }                                                                      \
        __syncthreads();                                                       \
    }

#define PHASE2(PI, Y)                                                          \
    {                                                                          \
        const int plane = (np4 + (PI)) * NCH + c;                              \
        float* op = out + (size_t)plane * PLANE;                               \
        _Pragma("unroll")                                                      \
        for (int k = 0; k < 4; ++k) {                                          \
            _Pragma("unroll")                                                  \
            for (int rr = 0; rr < 4; ++rr) {                                   \
                f4v o;                                                         \
                o.x = fmaxf(fmaf((float)Y[k * 16 + rr * 4 + 0], s, sh), 0.f);  \
                o.y = fmaxf(fmaf((float)Y[k * 16 + rr * 4 + 1], s, sh), 0.f);  \
                o.z = fmaxf(fmaf((float)Y[k * 16 + rr * 4 + 2], s, sh), 0.f);  \
                o.w = fmaxf(fmaf((float)Y[k * 16 + rr * 4 + 3], s, sh), 0.f);  \
                const int row = rg * 16 + k * 4 + rr;                          \
                __builtin_nontemporal_store(o, (f4v*)(op + row * HW + w4));    \
            }                                                                  \
        }                                                                      \
    }

__global__ __launch_bounds__(256, 2) void fused(const float* __restrict__ x,
                                                const float* __restrict__ wgt,
                                                const float* __restrict__ bias,
                                                const float* __restrict__ gamma,
                                                const float* __restrict__ beta,
                                                float* __restrict__ partials,
                                                float* __restrict__ out) {
    __shared__ float red[8];
    __shared__ float ssh[2];
    const int bid = blockIdx.x;        // 0..511
    const int c   = bid & 63;
    const int np4 = (bid >> 6) * 4;    // first n of this block's 4 planes
    const int t   = threadIdx.x;
    const int cg_ = t & 31, rg = t >> 5;
    const int w4  = cg_ * 4;
    const bool hasL = (cg_ != 0), hasR = (cg_ != 31);

    float W[9];
#pragma unroll
    for (int k = 0; k < 9; ++k) W[k] = wgt[c * 9 + k];
    const float bv = bias[c];

    h64v yA, yB, yC, yD;               // 4 planes x 64 px, packed fp16 (32 VGPR each)

    PHASE1(0, yA)
    PHASE1(1, yB)
    PHASE1(2, yC)
    PHASE1(3, yD)

    __threadfence();
    cg::this_grid().sync();

    // ---- stats fold: 32 lanes, coalesced ----
    if (t < 32) {
        float S = partials[c * 32 + t];
        float Q = partials[2048 + c * 32 + t];
#pragma unroll
        for (int off = 16; off; off >>= 1) {
            S += __shfl_xor(S, off);
            Q += __shfl_xor(Q, off);
        }
        if (t == 0) {
            float mean = S * COUNT_INV;
            float var  = fmaxf(Q * COUNT_INV - mean * mean, 0.f);
            float s    = gamma[c] * rsqrtf(var + EPSV);
            ssh[0] = s;
            ssh[1] = beta[c] - mean * s;   // conv bias already inside y
        }
    }
    __syncthreads();
    const float s  = ssh[0];
    const float sh = ssh[1];

    PHASE2(0, yA)
    PHASE2(1, yB)
    PHASE2(2, yC)
    PHASE2(3, yD)
}

// ---------------- fallback: round-5 two-pass (fp16 y staging) ----------------
__global__ __launch_bounds__(256) void pass_conv_stats(const float* __restrict__ x,
                                                       const float* __restrict__ wgt,
                                                       const float* __restrict__ bias,
                                                       _Float16* __restrict__ yh,
                                                       float* __restrict__ partials) {
    __shared__ float red[8];
    const int bid   = blockIdx.x;
    const int q     = bid & 3;
    const int plane = bid >> 2;
    const int c     = plane & 63;
    const int n     = plane >> 6;
    const int t     = threadIdx.x;
    const int cg    = t & 31, rg = t >> 5;
    const int w4    = cg * 4, r0 = q * 32 + rg * 4;
    const bool hasL = (cg != 0), hasR = (cg != 31);

    float W[9];
#pragma unroll
    for (int k = 0; k < 9; ++k) W[k] = wgt[c * 9 + k];
    const float bv = bias[c];
    const float* bp = x + (size_t)plane * PLANE;
    _Float16* yp = yh + (size_t)plane * PLANE;

    float v[6][6];
    load_win(bp, r0, w4, hasL, hasR, v);

    float sum = 0.f, sq = 0.f;
#pragma unroll
    for (int k = 0; k < 4; ++k) {
        float acc[4];
        conv_row(v[k], v[k + 1], v[k + 2], W, bv, acc);
        h4v hv;
        hv.x = (_Float16)acc[0]; hv.y = (_Float16)acc[1];
        hv.z = (_Float16)acc[2]; hv.w = (_Float16)acc[3];
        *(h4v*)(yp + (r0 + k) * HW + w4) = hv;
#pragma unroll
        for (int j = 0; j < 4; ++j) { sum += acc[j]; sq = fmaf(acc[j], acc[j], sq); }
    }
#pragma unroll
    for (int off = 32; off; off >>= 1) {
        sum += __shfl_down(sum, off);
        sq  += __shfl_down(sq, off);
    }
    const int wave = t >> 6, lane = t & 63;
    if (lane == 0) { red[wave] = sum; red[4 + wave] = sq; }
    __syncthreads();
    if (t == 0) {
        const int pi = n * 4 + q;
        partials[c * 128 + pi]         = red[0] + red[1] + red[2] + red[3];
        partials[NPART + c * 128 + pi] = red[4] + red[5] + red[6] + red[7];
    }
}

__global__ __launch_bounds__(256) void pass_norm(const _Float16* __restrict__ yh,
                                                 const float* __restrict__ partials,
                                                 const float* __restrict__ gamma,
                                                 const float* __restrict__ beta,
                                                 float* __restrict__ out) {
    const int bid   = blockIdx.x;
    const int q     = bid & 3;
    const int plane = bid >> 2;
    const int c     = plane & 63;
    const int t     = threadIdx.x;
    const int cg    = t & 31, rg = t >> 5;
    const int w4    = cg * 4, r0 = q * 32 + rg * 4;

    const _Float16* yp = yh + (size_t)plane * PLANE;
    h4v hv[4];
#pragma unroll
    for (int k = 0; k < 4; ++k)
        hv[k] = *(const h4v*)(yp + (r0 + k) * HW + w4);

    const int lane = t & 63;
    float S = partials[c * 128 + lane]         + partials[c * 128 + 64 + lane];
    float Q = partials[NPART + c * 128 + lane] + partials[NPART + c * 128 + 64 + lane];
#pragma unroll
    for (int off = 32; off; off >>= 1) {
        S += __shfl_xor(S, off);
        Q += __shfl_xor(Q, off);
    }
    const float mean = S * COUNT_INV;
    const float var  = fmaxf(Q * COUNT_INV - mean * mean, 0.f);
    const float s    = gamma[c] * rsqrtf(var + EPSV);
    const float sh   = beta[c] - mean * s;

    float* op = out + (size_t)plane * PLANE;
#pragma unroll
    for (int k = 0; k < 4; ++k) {
        f4v o;
        o.x = fmaxf(fmaf((float)hv[k].x, s, sh), 0.f);
        o.y = fmaxf(fmaf((float)hv[k].y, s, sh), 0.f);
        o.z = fmaxf(fmaf((float)hv[k].z, s, sh), 0.f);
        o.w = fmaxf(fmaf((float)hv[k].w, s, sh), 0.f);
        __builtin_nontemporal_store(o, (f4v*)(op + (r0 + k) * HW + w4));
    }
}

extern "C" void kernel_launch(void* const* d_in, const int* in_sizes, int n_in,
                              void* d_out, int out_size, void* d_ws, size_t ws_size,
                              hipStream_t stream) {
    const float* x     = (const float*)d_in[0];
    const float* w     = (const float*)d_in[1];
    const float* b     = (const float*)d_in[2];
    const float* gamma = (const float*)d_in[3];
    const float* beta  = (const float*)d_in[4];
    float* out = (float*)d_out;

    int nb = 0;
    hipError_t qe = hipOccupancyMaxActiveBlocksPerMultiprocessor(
        &nb, reinterpret_cast<const void*>(fused), 256, 0);

    if (qe == hipSuccess && nb >= 2) {
        float* parts = (float*)d_ws;
        const float* xa = x; const float* wa = w; const float* ba = b;
        const float* ga = gamma; const float* be = beta;
        float* pw = parts; float* oa = out;
        void* args[] = {&xa, &wa, &ba, &ga, &be, &pw, &oa};
        hipLaunchCooperativeKernel(reinterpret_cast<const void*>(fused),
                                   dim3(512), dim3(256), args, 0, stream);
    } else if (ws_size >= WS_NEED) {
        _Float16* yh  = (_Float16*)d_ws;
        float* parts  = (float*)d_ws + PART_OFF;
        pass_conv_stats<<<NB * NCH * NQ, 256, 0, stream>>>(x, w, b, yh, parts);
        pass_norm<<<NB * NCH * NQ, 256, 0, stream>>>(yh, parts, gamma, beta, out);
    }
}